// Round 14
// baseline (850.640 us; speedup 1.0000x reference)
//
#include <hip/hip_runtime.h>
#include <hip/hip_bf16.h>

// ---------------------------------------------------------------------------
// WeightOnlyLinear: y = x @ dequant4(qweight, scales, qzeros) + bias
//   x (8192,4096) fp32 | scales (32,12288) | bias (12288) | qweight (512,12288)
//   qzeros (32,1536) | out (8192,12288) fp32
// R14: R10 (pre-tiled fragment-major operands, 32x32x16 MFMA, ring-4 slots)
//      with K-64 PHASES: each phase consumes a slot PAIR ({0,1} or {2,3}),
//      32 MFMAs, ONE vmcnt(0) + ONE barrier. Halves per-MFMA sync overhead.
//      Body: reads(s0) -> stage next pair (8 gloads) -> MFMA x16 ->
//            reads(s1) -> MFMA x16 -> vm0 -> bar.
//      Safety: at the barrier all waves' reads of current pair retired
//      (lgkm drained before consuming MFMAs) and all stages of next pair
//      landed (vm0) -> next phase may read next-pair / overwrite current.
// ---------------------------------------------------------------------------

typedef __attribute__((ext_vector_type(8))) short short8;
typedef __attribute__((ext_vector_type(4))) float f32x4;
typedef __attribute__((ext_vector_type(16))) float f32x16;

__device__ __forceinline__ short f2bf(float f) {
  unsigned u = __float_as_uint(f);
  u += 0x7fffu + ((u >> 16) & 1u);
  return (short)(u >> 16);
}

__device__ __forceinline__ void gload_lds16(const void* g, void* l) {
  __builtin_amdgcn_global_load_lds(
      (const __attribute__((address_space(1))) void*)g,
      (__attribute__((address_space(3))) void*)l,
      16, 0, 0);
}

__device__ __forceinline__ void bar() {
  asm volatile("" ::: "memory");
  __builtin_amdgcn_s_barrier();
  asm volatile("" ::: "memory");
}
__device__ __forceinline__ void wait_vm0() {
  asm volatile("s_waitcnt vmcnt(0)" ::: "memory");
}

// ---------------------------------------------------------------------------
// Pass 1: dequant qweight -> B' fragment-major tiles.
// Tile (nb256, h32) = 16KB; chunk c = cb*128 + kh*64 + kq2*32 + lane31.
// ---------------------------------------------------------------------------
__global__ __launch_bounds__(256) void dequant_tile_kernel(
    const int* __restrict__ qweight, const int* __restrict__ qzeros,
    const float* __restrict__ scales, short* __restrict__ Bt,
    int N, int K) {
  const int kt = K >> 5;
  const int bx = blockIdx.x;
  const int nb = bx / kt, h = bx - nb * kt;
  const int t = threadIdx.x;
  const int n = nb * 256 + t;
  const int g = h >> 2;
  const float sc = scales[(size_t)g * N + n];
  const int zw = qzeros[(size_t)g * (N >> 3) + (n >> 3)];
  const float zs = -(float)(((zw >> ((n & 7) * 4)) & 15) + 1) * sc;
  char* dst = (char*)Bt + (size_t)bx * 16384;
#pragma unroll
  for (int kw = 0; kw < 4; ++kw) {
    const int w = qweight[(size_t)(h * 4 + kw) * N + n];
    short8 v;
#pragma unroll
    for (int e = 0; e < 8; ++e)
      v[e] = f2bf(fmaf((float)((w >> (4 * e)) & 15), sc, zs));
    const int c = ((t >> 5) << 7) + ((kw >> 1) << 6) + ((kw & 1) << 5) + (t & 31);
    *(short8*)(dst + c * 16) = v;
  }
}

// ---------------------------------------------------------------------------
// Pass 2: x fp32 -> A' fragment-major tiles (same chunk mapping).
// ---------------------------------------------------------------------------
__global__ __launch_bounds__(256) void cvt_tile_kernel(
    const float* __restrict__ x, short* __restrict__ xb, int K) {
  const int kt = K >> 5;
  const int bx = blockIdx.x;
  const int mb = bx / kt, h = bx - mb * kt;
  const float* xs = x + (size_t)mb * 256 * K + h * 32;
  char* dst = (char*)xb + (size_t)bx * 16384;
#pragma unroll
  for (int p = 0; p < 4; ++p) {
    const int t2 = p * 256 + threadIdx.x;
    const int row = t2 >> 2, kq = t2 & 3;
    const float* s = xs + (size_t)row * K + kq * 8;
    float4 f0 = *(const float4*)s;
    float4 f1 = *(const float4*)(s + 4);
    short8 v;
    v[0] = f2bf(f0.x); v[1] = f2bf(f0.y); v[2] = f2bf(f0.z); v[3] = f2bf(f0.w);
    v[4] = f2bf(f1.x); v[5] = f2bf(f1.y); v[6] = f2bf(f1.z); v[7] = f2bf(f1.w);
    const int c = ((row >> 5) << 7) + ((kq >> 1) << 6) + ((kq & 1) << 5) + (row & 31);
    *(short8*)(dst + c * 16) = v;
  }
}

// ---------------------------------------------------------------------------
// Pass 3 (R14): 256x256 GEMM, 512 threads = 8 waves (2M x 4N), wave 128x64.
// MFMA 32x32x16; wave tile 4x2 frags of 32x32.
// LDS ring: 4 slots x 32KB fragment-major. Phase = K-64 = slot pair.
// Even phase reads slots {0,1}, stages K-halves (base+2,+3) -> slots {2,3};
// odd reads {2,3}, stages (base+4,+5) -> {0,1}. One vm0+bar per phase.
// ---------------------------------------------------------------------------
#define GBM 256
#define GBN 256

__global__ __launch_bounds__(512, 2) void gemm256_kernel(
    const short* __restrict__ At, const short* __restrict__ Bt,
    const float* __restrict__ bias, float* __restrict__ C,
    int M, int N, int K) {
  __shared__ __align__(16) char lds[4][32768];
  const int tid = threadIdx.x;
  const int nbx = N / GBN;
  const int nwg = gridDim.x;
  int bid = blockIdx.x;
  if ((nwg & 7) == 0) bid = (bid & 7) * (nwg >> 3) + (bid >> 3);  // T1
  const int mb = bid / nbx;
  const int nb = bid % nbx;
  const int bm = mb * GBM, bn = nb * GBN;

  const int wid = tid >> 6, lane = tid & 63;
  const int wr = wid >> 2, wc = wid & 3;  // 2x4 wave grid
  const int l31 = lane & 31;
  const int lq2 = lane >> 5;

  const int P = K >> 5;   // K-halves; K % 256 == 0 -> P % 8 == 0
  const int NP = P >> 1;  // K-64 phases (even count)

  char* lb = &lds[0][0];

  // ds_read base pointers [hi = slot>>1]; (slot&1)*32768 + i*2048 + kh*1024
  const char* aB[2];
  const char* bB[2];
  aB[0] = lb + wr * 8192 + lane * 16;          // rb = wr*4 + i
  aB[1] = aB[0] + 65536;
  bB[0] = lb + 16384 + wc * 4096 + lane * 16;  // cb = wc*2 + j
  bB[1] = bB[0] + 65536;

  // staging: pre-tiled sources, contiguous per K-half (16KB each)
  const char* gA = (const char*)At + (size_t)mb * P * 16384;
  const char* gB = (const char*)Bt + (size_t)nb * P * 16384;
  char* dstA0 = lb + tid * 16;
  char* dstA1 = dstA0 + 8192;
  char* dstB0 = dstA0 + 16384;
  char* dstB1 = dstA0 + 24576;
  const size_t t16 = (size_t)tid * 16;

#define STAGE(NSL, ASRC, BSRC)                               \
  do {                                                       \
    gload_lds16((ASRC) + t16, dstA0 + (NSL) * 32768);        \
    gload_lds16((ASRC) + t16 + 8192, dstA1 + (NSL) * 32768); \
    gload_lds16((BSRC) + t16, dstB0 + (NSL) * 32768);        \
    gload_lds16((BSRC) + t16 + 8192, dstB1 + (NSL) * 32768); \
  } while (0)

#define RDFRAG(SL, A, B)                                                      \
  do {                                                                        \
    _Pragma("unroll") for (int i = 0; i < 4; ++i)                             \
        _Pragma("unroll") for (int kh = 0; kh < 2; ++kh) A[i][kh] =           \
        *(const short8*)(aB[(SL) >> 1] + ((SL)&1) * 32768 + i * 2048 +        \
                         kh * 1024);                                          \
    _Pragma("unroll") for (int j = 0; j < 2; ++j)                             \
        _Pragma("unroll") for (int kh = 0; kh < 2; ++kh) B[j][kh] =           \
        *(const short8*)(bB[(SL) >> 1] + ((SL)&1) * 32768 + j * 2048 +        \
                         kh * 1024);                                          \
  } while (0)

  f32x16 acc[4][2] = {};

#define MFMA16(A, B)                                                          \
  do {                                                                        \
    __builtin_amdgcn_s_setprio(1);                                            \
    _Pragma("unroll") for (int kh = 0; kh < 2; ++kh)                          \
        _Pragma("unroll") for (int i = 0; i < 4; ++i)                         \
        _Pragma("unroll") for (int j = 0; j < 2; ++j) acc[i][j] =             \
            __builtin_amdgcn_mfma_f32_32x32x16_bf16(A[i][kh], B[j][kh],       \
                                                    acc[i][j], 0, 0, 0);      \
    __builtin_amdgcn_s_setprio(0);                                            \
  } while (0)

// One K-64 phase: read slot S0, stage next pair (T0,T1 from offsets O0,O1),
// MFMA, read slot S1, MFMA, vm0, bar. ST=false -> no staging, no sync.
#define PHASE64(S0, S1, T0, T1, O0, O1, ST)                                   \
  do {                                                                        \
    short8 a0[4][2], b0[2][2];                                                \
    RDFRAG(S0, a0, b0);                                                       \
    if (ST) {                                                                 \
      STAGE(T0, pA + (O0) * 16384, pB + (O0) * 16384);                        \
      STAGE(T1, pA + (O1) * 16384, pB + (O1) * 16384);                        \
    }                                                                         \
    MFMA16(a0, b0);                                                           \
    short8 a1[4][2], b1[2][2];                                                \
    RDFRAG(S1, a1, b1);                                                       \
    MFMA16(a1, b1);                                                           \
    if (ST) { wait_vm0(); }                                                   \
    bar();                                                                    \
  } while (0)

  // prologue: stage K-halves 0,1 into slots 0,1 (8 loads); drain; bar.
  STAGE(0, gA, gB);
  STAGE(1, gA + 16384, gB + 16384);
  wait_vm0();
  bar();

  // main loop: iteration it = phases 2it (slots 0,1) and 2it+1 (slots 2,3).
  // pA points at K-half 4it. Even stages +2,+3 -> slots 2,3; odd stages
  // +4,+5 -> slots 0,1.
  const char* pA = gA;
  const char* pB = gB;
  const int nIt = NP / 2 - 1;
  for (int it = 0; it < nIt; ++it) {
    PHASE64(0, 1, 2, 3, 2, 3, true);
    PHASE64(2, 3, 0, 1, 4, 5, true);
    pA += 65536;
    pB += 65536;
  }
  // tail iteration: even phase stages last pair (P-2,P-1); odd stages none.
  PHASE64(0, 1, 2, 3, 2, 3, true);
  PHASE64(2, 3, 0, 1, 4, 5, false);

#undef PHASE64
#undef MFMA16
#undef RDFRAG
#undef STAGE

  // epilogue: C = acc + bias.
  // 32x32 C/D map: col = lane&31, row = (reg&3) + 8*(reg>>2) + 4*(lane>>5)
  const int crow0 = bm + wr * 128 + 4 * lq2;
#pragma unroll
  for (int j = 0; j < 2; ++j) {
    const int ccol = bn + wc * 64 + j * 32 + l31;
    const float bv = bias[ccol];
#pragma unroll
    for (int i = 0; i < 4; ++i) {
#pragma unroll
      for (int reg = 0; reg < 16; ++reg) {
        const int row = crow0 + i * 32 + (reg & 3) + 8 * (reg >> 2);
        C[(size_t)row * N + ccol] = acc[i][j][reg] + bv;
      }
    }
  }
}

// ---------------------------------------------------------------------------
// Fallback prepasses (linear layouts) for non-256-divisible shapes.
// ---------------------------------------------------------------------------
__global__ __launch_bounds__(256) void dequant_kernel(
    const int* __restrict__ qweight, const int* __restrict__ qzeros,
    const float* __restrict__ scales, short* __restrict__ Wt,
    int in_f, int out_f) {
  __shared__ __align__(16) short T[64][72];
  const int n0 = blockIdx.x * 64;
  const int k0 = blockIdx.y * 64;
  const int t = threadIdx.x;
  const int nl = t & 63;
  const int kw = t >> 6;
  const int n = n0 + nl;
  const int g = k0 >> 7;
  const float sc = scales[(size_t)g * out_f + n];
  const int zpw = qzeros[(size_t)g * (out_f >> 3) + (n >> 3)];
  const float zp = (float)(((zpw >> ((n & 7) * 4)) & 15) + 1);
  const float zs = zp * sc;
#pragma unroll
  for (int rr = 0; rr < 2; ++rr) {
    const int kwi = kw + rr * 4;
    const int w = qweight[(size_t)((k0 >> 3) + kwi) * out_f + n];
    short8 v;
#pragma unroll
    for (int e = 0; e < 8; ++e) {
      float f = (float)((w >> (4 * e)) & 15) * sc - zs;
      v[e] = f2bf(f);
    }
    *(short8*)&T[nl][kwi * 8] = v;
  }
  __syncthreads();
#pragma unroll
  for (int rr = 0; rr < 2; ++rr) {
    const int c = rr * 256 + t;
    const int row = c >> 3, ch = c & 7;
    *(short8*)&Wt[(size_t)(n0 + row) * in_f + k0 + ch * 8] =
        *(const short8*)&T[row][ch * 8];
  }
}

__global__ __launch_bounds__(256) void cvt_kernel(
    const float* __restrict__ x, short* __restrict__ xb, long n8) {
  long i = (long)blockIdx.x * blockDim.x + threadIdx.x;
  if (i >= n8) return;
  const float* src = x + i * 8;
  float4 a = *(const float4*)src;
  float4 b = *(const float4*)(src + 4);
  short8 v;
  v[0] = f2bf(a.x); v[1] = f2bf(a.y); v[2] = f2bf(a.z); v[3] = f2bf(a.w);
  v[4] = f2bf(b.x); v[5] = f2bf(b.y); v[6] = f2bf(b.z); v[7] = f2bf(b.w);
  *(short8*)(xb + i * 8) = v;
}

// ---------------------------------------------------------------------------
// 128x128x64 GEMM (fallback for non-256-divisible shapes).
// ---------------------------------------------------------------------------
#define BM 128
#define BN 128
#define BK 64

template <bool A_BF16>
__global__ __launch_bounds__(256) void gemm_bias_kernel(
    const void* __restrict__ Av, const short* __restrict__ Bt,
    const float* __restrict__ bias, float* __restrict__ C,
    int M, int N, int K) {
  __shared__ __align__(16) short As[BM * BK];
  __shared__ __align__(16) short Bs[BN * BK];
  const int tid = threadIdx.x;
  const int bm = blockIdx.y * BM;
  const int bn = blockIdx.x * BN;
  const int wid = tid >> 6, lane = tid & 63;
  const int wr = wid >> 1, wc = wid & 1;
  const int lrow = lane & 15;
  const int lk = (lane >> 4) * 8;

  f32x4 acc[4][4] = {};

  for (int kt = 0; kt < K; kt += BK) {
    if constexpr (A_BF16) {
      const short* A = (const short*)Av;
#pragma unroll
      for (int r = 0; r < 4; ++r) {
        const int c = r * 256 + tid;
        const int row = c >> 3, ch = c & 7;
        gload_lds16(A + (size_t)(bm + row) * K + kt + ch * 8,
                    (char*)As + c * 16);
      }
    } else {
      const float* A = (const float*)Av;
#pragma unroll
      for (int r = 0; r < 4; ++r) {
        const int c = r * 256 + tid;
        const int row = c >> 3, ch = c & 7;
        const float* src = A + (size_t)(bm + row) * K + kt + ch * 8;
        float4 f0 = *(const float4*)src;
        float4 f1 = *(const float4*)(src + 4);
        short8 v;
        v[0] = f2bf(f0.x); v[1] = f2bf(f0.y); v[2] = f2bf(f0.z); v[3] = f2bf(f0.w);
        v[4] = f2bf(f1.x); v[5] = f2bf(f1.y); v[6] = f2bf(f1.z); v[7] = f2bf(f1.w);
        *(short8*)((char*)As + c * 16) = v;
      }
    }
#pragma unroll
    for (int r = 0; r < 4; ++r) {
      const int c = r * 256 + tid;
      const int row = c >> 3, ch = c & 7;
      gload_lds16(Bt + (size_t)(bn + row) * K + kt + ch * 8,
                  (char*)Bs + c * 16);
    }
    __syncthreads();
#pragma unroll
    for (int kk = 0; kk < 2; ++kk) {
      short8 af[4], bf[4];
#pragma unroll
      for (int i = 0; i < 4; ++i)
        af[i] = *(const short8*)&As[(wr * 64 + i * 16 + lrow) * BK + kk * 32 + lk];
#pragma unroll
      for (int j = 0; j < 4; ++j)
        bf[j] = *(const short8*)&Bs[(wc * 64 + j * 16 + lrow) * BK + kk * 32 + lk];
#pragma unroll
      for (int i = 0; i < 4; ++i)
#pragma unroll
        for (int j = 0; j < 4; ++j)
          acc[i][j] = __builtin_amdgcn_mfma_f32_16x16x32_bf16(
              af[i], bf[j], acc[i][j], 0, 0, 0);
    }
    __syncthreads();
  }

  const int crow0 = bm + wr * 64 + (lane >> 4) * 4;
  const int ccol0 = bn + wc * 64 + (lane & 15);
#pragma unroll
  for (int j = 0; j < 4; ++j) {
    const float bv = bias[ccol0 + j * 16];
#pragma unroll
    for (int i = 0; i < 4; ++i) {
#pragma unroll
      for (int r = 0; r < 4; ++r) {
        C[(size_t)(crow0 + i * 16 + r) * N + ccol0 + j * 16] = acc[i][j][r] + bv;
      }
    }
  }
}

// ---------------------------------------------------------------------------
// Last-resort fallback: naive fused dequant GEMM.
// ---------------------------------------------------------------------------
__global__ __launch_bounds__(256) void naive_kernel(
    const float* __restrict__ x, const float* __restrict__ scales,
    const float* __restrict__ bias, const int* __restrict__ qw,
    const int* __restrict__ qz, float* __restrict__ out,
    int M, int K, int N) {
  long idx = (long)blockIdx.x * blockDim.x + threadIdx.x;
  if (idx >= (long)M * N) return;
  const int n = (int)(idx % N);
  const int m = (int)(idx / N);
  float acc = 0.f;
  for (int g = 0; g < K / 128; ++g) {
    const float sc = scales[(size_t)g * N + n];
    const float zp =
        (float)(((qz[(size_t)g * (N >> 3) + (n >> 3)] >> ((n & 7) * 4)) & 15) + 1);
    const float zs = zp * sc;
    for (int kw = 0; kw < 16; ++kw) {
      const int w = qw[(size_t)(g * 16 + kw) * N + n];
      const float* xp = &x[(size_t)m * K + g * 128 + kw * 8];
#pragma unroll
      for (int e = 0; e < 8; ++e)
        acc += xp[e] * ((float)((w >> (4 * e)) & 15) * sc - zs);
    }
  }
  out[idx] = acc + bias[n];
}

// ---------------------------------------------------------------------------
extern "C" void kernel_launch(void* const* d_in, const int* in_sizes, int n_in,
                              void* d_out, int out_size, void* d_ws,
                              size_t ws_size, hipStream_t stream) {
  const float* x = (const float*)d_in[0];
  const float* scales = (const float*)d_in[1];
  const float* bias = (const float*)d_in[2];
  const int* qweight = (const int*)d_in[3];
  const int* qzeros = (const int*)d_in[4];
  float* out = (float*)d_out;

  const int out_f = in_sizes[2];            // 12288
  const int kwords = in_sizes[3] / out_f;   // 512
  const int in_f = kwords * 8;              // 4096
  const int tokens = in_sizes[0] / in_f;    // 8192
  const int M = tokens, K = in_f, N = out_f;

  const size_t wt_bytes = (size_t)K * N * sizeof(short);
  const size_t xb_bytes = (size_t)M * K * sizeof(short);

  const bool div128 = (M % BM == 0) && (N % BN == 0) && (K % BK == 0) &&
                      (K % 128 == 0) && (N % 64 == 0);
  const bool div256 = (M % GBM == 0) && (N % GBN == 0) && (K % 256 == 0);

  if (div256 && ws_size >= wt_bytes + xb_bytes) {
    // R14 pre-tiled path
    short* Btile = (short*)d_ws;                        // B' fragment tiles
    short* Atile = (short*)((char*)d_ws + wt_bytes);    // A' fragment tiles
    const int kt = K >> 5;
    dequant_tile_kernel<<<(N / 256) * kt, 256, 0, stream>>>(
        qweight, qzeros, scales, Btile, N, K);
    cvt_tile_kernel<<<(M / 256) * kt, 256, 0, stream>>>(x, Atile, K);
    gemm256_kernel<<<(M / GBM) * (N / GBN), 512, 0, stream>>>(
        Atile, Btile, bias, out, M, N, K);
  } else if (div128 && ws_size >= wt_bytes + xb_bytes) {
    short* Wt = (short*)d_ws;
    short* xb = (short*)((char*)d_ws + wt_bytes);
    dequant_kernel<<<dim3(N / 64, K / 64), 256, 0, stream>>>(
        qweight, qzeros, scales, Wt, K, N);
    const long n8 = (long)M * K / 8;
    cvt_kernel<<<(int)((n8 + 255) / 256), 256, 0, stream>>>(x, xb, n8);
    gemm_bias_kernel<true><<<dim3(N / BN, M / BM), 256, 0, stream>>>(
        xb, Wt, bias, out, M, N, K);
  } else if (div128 && ws_size >= wt_bytes) {
    short* Wt = (short*)d_ws;
    dequant_kernel<<<dim3(N / 64, K / 64), 256, 0, stream>>>(
        qweight, qzeros, scales, Wt, K, N);
    gemm_bias_kernel<false><<<dim3(N / BN, M / BM), 256, 0, stream>>>(
        x, Wt, bias, out, M, N, K);
  } else {
    const long total = (long)M * N;
    naive_kernel<<<(int)((total + 255) / 256), 256, 0, stream>>>(
        x, scales, bias, qweight, qzeros, out, M, K, N);
  }
}

// Round 15
// 800.612 us; speedup vs baseline: 1.0625x; 1.0625x over previous
//
#include <hip/hip_runtime.h>
#include <hip/hip_bf16.h>

// ---------------------------------------------------------------------------
// WeightOnlyLinear: y = x @ dequant4(qweight, scales, qzeros) + bias
//   x (8192,4096) fp32 | scales (32,12288) | bias (12288) | qweight (512,12288)
//   qzeros (32,1536) | out (8192,12288) fp32
// R15: faithful m201 8-phase dual-buffer schedule on pre-tiled fragment-major
//   operands. 16x16x32 MFMA, 8 waves (2Mx4N), wave 128x64, acc 8x4 f32x4.
//   K-64 tiles; buf[2] x (A 32KB + B 32KB). Per iteration (tiles t,t+1):
//   phi0: rdA(mh0)+rdB(nh0) [12]; stage (t+1)u1 | phi1: rdB(nh1)[4]; u2
//   phi2: rdA(mh1)[8]; u3 | phi3: stage (t+2)u0; vm2  <- no reads: buf free
//   phi4-7 mirror on buf1 (stage (t+2)u1..u3, (t+3)u0; vm2 at phi7).
//   Each phase: {reads; stage; BAR; setprio 16 MFMA; BAR}. Reads of a tile
//   complete by phi2 of its window (frags in regs) -> staging its buffer at
//   phi3-6 is barrier-proven safe. vmcnt(2) only at phi3/phi7.
// ---------------------------------------------------------------------------

typedef __attribute__((ext_vector_type(8))) short short8;
typedef __attribute__((ext_vector_type(4))) float f32x4;

__device__ __forceinline__ short f2bf(float f) {
  unsigned u = __float_as_uint(f);
  u += 0x7fffu + ((u >> 16) & 1u);
  return (short)(u >> 16);
}

__device__ __forceinline__ void gload_lds16(const void* g, void* l) {
  __builtin_amdgcn_global_load_lds(
      (const __attribute__((address_space(1))) void*)g,
      (__attribute__((address_space(3))) void*)l,
      16, 0, 0);
}

__device__ __forceinline__ void bar() {
  asm volatile("" ::: "memory");
  __builtin_amdgcn_s_barrier();
  asm volatile("" ::: "memory");
}
__device__ __forceinline__ void wait_vm2() {
  asm volatile("s_waitcnt vmcnt(2)" ::: "memory");
}
__device__ __forceinline__ void wait_vm0() {
  asm volatile("s_waitcnt vmcnt(0)" ::: "memory");
}

// ---------------------------------------------------------------------------
// Pass 1: dequant qweight -> B' fragment-major K-64 tiles (16x16x32 frags).
// Tile (nb, kt) = 32KB: chunk c = cb*128 + ks*64 + lane; lane l holds
// col = cb*16 + (l&15), k = ks*32 + ((l>>4)&3)*8 .. +8. One qweight word
// == one chunk. grid = (N/256)*(K/64), ordered (nb, kt).
// ---------------------------------------------------------------------------
__global__ __launch_bounds__(256) void dequant_tile_kernel(
    const int* __restrict__ qweight, const int* __restrict__ qzeros,
    const float* __restrict__ scales, short* __restrict__ Bt,
    int N, int K) {
  const int ktn = K >> 6;
  const int bx = blockIdx.x;
  const int nb = bx / ktn, kt = bx - nb * ktn;
  const int t = threadIdx.x;
  const int k8 = ((t >> 6) & 1) * 4 + ((t >> 4) & 3);  // thread-invariant
  const int kw = kt * 8 + k8;                           // qweight row
  const int g = kt >> 1;                                // GROUPSIZE=128
  char* dst = (char*)Bt + (size_t)bx * 32768;
#pragma unroll
  for (int p = 0; p < 8; ++p) {
    const int c = p * 256 + t;
    const int col = (p * 2 + (t >> 7)) * 16 + (t & 15);
    const int n = nb * 256 + col;
    const float sc = scales[(size_t)g * N + n];
    const int zw = qzeros[(size_t)g * (N >> 3) + (n >> 3)];
    const float zs = -(float)(((zw >> ((n & 7) * 4)) & 15) + 1) * sc;
    const int w = qweight[(size_t)kw * N + n];
    short8 v;
#pragma unroll
    for (int e = 0; e < 8; ++e)
      v[e] = f2bf(fmaf((float)((w >> (4 * e)) & 15), sc, zs));
    *(short8*)(dst + c * 16) = v;
  }
}

// ---------------------------------------------------------------------------
// Pass 2: x fp32 -> A' fragment-major K-64 tiles (same chunk mapping,
// row instead of col). grid = (M/256)*(K/64), ordered (mb, kt).
// ---------------------------------------------------------------------------
__global__ __launch_bounds__(256) void cvt_tile_kernel(
    const float* __restrict__ x, short* __restrict__ xb, int K) {
  const int ktn = K >> 6;
  const int bx = blockIdx.x;
  const int mb = bx / ktn, kt = bx - mb * ktn;
  const int t = threadIdx.x;
  const int k8 = ((t >> 6) & 1) * 4 + ((t >> 4) & 3);
  const float* xs = x + kt * 64 + k8 * 8;
  char* dst = (char*)xb + (size_t)bx * 32768;
#pragma unroll
  for (int p = 0; p < 8; ++p) {
    const int c = p * 256 + t;
    const int row = mb * 256 + (p * 2 + (t >> 7)) * 16 + (t & 15);
    const float* s = xs + (size_t)row * K;
    float4 f0 = *(const float4*)s;
    float4 f1 = *(const float4*)(s + 4);
    short8 v;
    v[0] = f2bf(f0.x); v[1] = f2bf(f0.y); v[2] = f2bf(f0.z); v[3] = f2bf(f0.w);
    v[4] = f2bf(f1.x); v[5] = f2bf(f1.y); v[6] = f2bf(f1.z); v[7] = f2bf(f1.w);
    *(short8*)(dst + c * 16) = v;
  }
}

// ---------------------------------------------------------------------------
// Pass 3 (R15): 256x256 GEMM, 512 threads = 8 waves (2M x 4N), wave 128x64.
// MFMA 16x16x32; acc f32x4[8][4]. LDS: buf[2] x 64KB (A @0, B @32768).
// Units (16KB): u0=A-lo, u1=A-hi, u2=B-lo, u3=B-hi; stage = 2 gloads.
// ---------------------------------------------------------------------------
#define GBM 256
#define GBN 256

__global__ __launch_bounds__(512, 2) void gemm256_kernel(
    const short* __restrict__ At, const short* __restrict__ Bt,
    const float* __restrict__ bias, float* __restrict__ C,
    int M, int N, int K) {
  __shared__ __align__(16) char lds[2][65536];
  const int tid = threadIdx.x;
  const int nbx = N / GBN;
  const int nwg = gridDim.x;
  int bid = blockIdx.x;
  if ((nwg & 7) == 0) bid = (bid & 7) * (nwg >> 3) + (bid >> 3);  // T1
  const int mb = bid / nbx;
  const int nb = bid % nbx;
  const int bm = mb * GBM, bn = nb * GBN;

  const int wid = tid >> 6, lane = tid & 63;
  const int wr = wid >> 2, wc = wid & 3;  // 2x4 wave grid

  const int KT = K >> 6;   // K-64 tiles; KT % 4 == 0 (K % 256 == 0)
  const int NI = KT >> 1;  // iterations

  char* lb = &lds[0][0];

  // frag read bases: A frag (rb = wr*8 + mh*4 + i, ks) at
  //   buf*65536 + rb*2048 + ks*1024 + lane*16; B: +32768, cb = wc*4 + j.
  const char* aBase[2];
  const char* bBase[2];
  aBase[0] = lb + wr * 16384 + lane * 16;
  aBase[1] = aBase[0] + 65536;
  bBase[0] = lb + 32768 + wc * 8192 + lane * 16;
  bBase[1] = bBase[0] + 65536;

  // staging: tile tau's unit u source = (u<2 ? A' : B') + tau*32768 +
  //   (u&1)*16384 + tid*16 (+8192 for the second gload). dst linear.
  const char* gA = (const char*)At + (size_t)mb * KT * 32768;
  const char* gB = (const char*)Bt + (size_t)nb * KT * 32768;
  const size_t t16 = (size_t)tid * 16;
  char* dstBase = lb + tid * 16;

#define STU(BUF, U, TOFF)                                                \
  do {                                                                   \
    const char* s_ =                                                     \
        ((U) < 2 ? pA + (TOFF) : pB + (TOFF)) + ((U)&1) * 16384 + t16;   \
    char* d_ = dstBase + (BUF)*65536 + (U)*16384;                        \
    gload_lds16(s_, d_);                                                 \
    gload_lds16(s_ + 8192, d_ + 8192);                                   \
  } while (0)

  short8 aR[4][2], bR[4][2];

#define RDA(BUF, MH)                                                     \
  do {                                                                   \
    _Pragma("unroll") for (int i = 0; i < 4; ++i)                        \
        _Pragma("unroll") for (int ks = 0; ks < 2; ++ks) aR[i][ks] =     \
        *(const short8*)(aBase[BUF] + (MH)*8192 + i * 2048 + ks * 1024); \
  } while (0)

#define RDB(BUF, NH)                                                     \
  do {                                                                   \
    _Pragma("unroll") for (int j = 0; j < 2; ++j)                        \
        _Pragma("unroll") for (int ks = 0; ks < 2; ++ks)                 \
        bR[(NH)*2 + j][ks] =                                             \
        *(const short8*)(bBase[BUF] + (NH)*4096 + j * 2048 + ks * 1024); \
  } while (0)

  f32x4 acc[8][4] = {};

#define MFMA16(MH, NH)                                                   \
  do {                                                                   \
    __builtin_amdgcn_s_setprio(1);                                       \
    _Pragma("unroll") for (int ks = 0; ks < 2; ++ks)                     \
        _Pragma("unroll") for (int i = 0; i < 4; ++i)                    \
        _Pragma("unroll") for (int j = 0; j < 2; ++j)                    \
        acc[(MH)*4 + i][(NH)*2 + j] =                                    \
            __builtin_amdgcn_mfma_f32_16x16x32_bf16(                     \
                aR[i][ks], bR[(NH)*2 + j][ks],                           \
                acc[(MH)*4 + i][(NH)*2 + j], 0, 0, 0);                   \
    __builtin_amdgcn_s_setprio(0);                                       \
  } while (0)

  // --- prologue: tile0 u0-u3 -> buf0, tile1 u0 -> buf1; vm2 -> tile0 in ---
  const char* pA = gA;
  const char* pB = gB;
  STU(0, 0, 0); STU(0, 1, 0); STU(0, 2, 0); STU(0, 3, 0);
  STU(1, 0, 32768);
  wait_vm2();
  bar();

  // --- main loop: NI-1 full iterations ---
  for (int n = 0; n < NI - 1; ++n) {
    // phi0
    RDA(0, 0); RDB(0, 0);
    STU(1, 1, 32768);
    bar(); MFMA16(0, 0); bar();
    // phi1
    RDB(0, 1);
    STU(1, 2, 32768);
    bar(); MFMA16(0, 1); bar();
    // phi2
    RDA(0, 1);
    STU(1, 3, 32768);
    bar(); MFMA16(1, 0); bar();
    // phi3 (no reads -> buf0 free; stage (t+2)u0; tile t+1 confirmed)
    STU(0, 0, 65536);
    wait_vm2();
    bar(); MFMA16(1, 1); bar();
    // phi4
    RDA(1, 0); RDB(1, 0);
    STU(0, 1, 65536);
    bar(); MFMA16(0, 0); bar();
    // phi5
    RDB(1, 1);
    STU(0, 2, 65536);
    bar(); MFMA16(0, 1); bar();
    // phi6
    RDA(1, 1);
    STU(0, 3, 65536);
    bar(); MFMA16(1, 0); bar();
    // phi7 (no reads -> buf1 free; stage (t+3)u0; tile t+2 confirmed)
    STU(1, 0, 98304);
    wait_vm2();
    bar(); MFMA16(1, 1); bar();
    pA += 65536;
    pB += 65536;
  }

  // --- tail iteration (tiles KT-2, KT-1): stage only (t+1)u1..u3 ---
  RDA(0, 0); RDB(0, 0);
  STU(1, 1, 32768);
  bar(); MFMA16(0, 0); bar();
  RDB(0, 1);
  STU(1, 2, 32768);
  bar(); MFMA16(0, 1); bar();
  RDA(0, 1);
  STU(1, 3, 32768);
  bar(); MFMA16(1, 0); bar();
  wait_vm0();
  bar(); MFMA16(1, 1); bar();
  RDA(1, 0); RDB(1, 0);
  bar(); MFMA16(0, 0); bar();
  RDB(1, 1);
  bar(); MFMA16(0, 1); bar();
  RDA(1, 1);
  bar(); MFMA16(1, 0); bar();
  MFMA16(1, 1);

#undef MFMA16
#undef RDB
#undef RDA
#undef STU

  // --- epilogue: C = acc + bias. 16x16 C/D: col=lane&15, row=(lane>>4)*4+r
  const int crow0 = bm + wr * 128 + (lane >> 4) * 4;
  const int ccol0 = bn + wc * 64 + (lane & 15);
#pragma unroll
  for (int fj = 0; fj < 4; ++fj) {
    const float bv = bias[ccol0 + fj * 16];
#pragma unroll
    for (int fi = 0; fi < 8; ++fi) {
#pragma unroll
      for (int r = 0; r < 4; ++r) {
        C[(size_t)(crow0 + fi * 16 + r) * N + ccol0 + fj * 16] =
            acc[fi][fj][r] + bv;
      }
    }
  }
}

// ---------------------------------------------------------------------------
// Fallback prepasses (linear layouts) for non-256-divisible shapes.
// ---------------------------------------------------------------------------
__global__ __launch_bounds__(256) void dequant_kernel(
    const int* __restrict__ qweight, const int* __restrict__ qzeros,
    const float* __restrict__ scales, short* __restrict__ Wt,
    int in_f, int out_f) {
  __shared__ __align__(16) short T[64][72];
  const int n0 = blockIdx.x * 64;
  const int k0 = blockIdx.y * 64;
  const int t = threadIdx.x;
  const int nl = t & 63;
  const int kw = t >> 6;
  const int n = n0 + nl;
  const int g = k0 >> 7;
  const float sc = scales[(size_t)g * out_f + n];
  const int zpw = qzeros[(size_t)g * (out_f >> 3) + (n >> 3)];
  const float zp = (float)(((zpw >> ((n & 7) * 4)) & 15) + 1);
  const float zs = zp * sc;
#pragma unroll
  for (int rr = 0; rr < 2; ++rr) {
    const int kwi = kw + rr * 4;
    const int w = qweight[(size_t)((k0 >> 3) + kwi) * out_f + n];
    short8 v;
#pragma unroll
    for (int e = 0; e < 8; ++e) {
      float f = (float)((w >> (4 * e)) & 15) * sc - zs;
      v[e] = f2bf(f);
    }
    *(short8*)&T[nl][kwi * 8] = v;
  }
  __syncthreads();
#pragma unroll
  for (int rr = 0; rr < 2; ++rr) {
    const int c = rr * 256 + t;
    const int row = c >> 3, ch = c & 7;
    *(short8*)&Wt[(size_t)(n0 + row) * in_f + k0 + ch * 8] =
        *(const short8*)&T[row][ch * 8];
  }
}

__global__ __launch_bounds__(256) void cvt_kernel(
    const float* __restrict__ x, short* __restrict__ xb, long n8) {
  long i = (long)blockIdx.x * blockDim.x + threadIdx.x;
  if (i >= n8) return;
  const float* src = x + i * 8;
  float4 a = *(const float4*)src;
  float4 b = *(const float4*)(src + 4);
  short8 v;
  v[0] = f2bf(a.x); v[1] = f2bf(a.y); v[2] = f2bf(a.z); v[3] = f2bf(a.w);
  v[4] = f2bf(b.x); v[5] = f2bf(b.y); v[6] = f2bf(b.z); v[7] = f2bf(b.w);
  *(short8*)(xb + i * 8) = v;
}

// ---------------------------------------------------------------------------
// 128x128x64 GEMM (fallback for non-256-divisible shapes).
// ---------------------------------------------------------------------------
#define BM 128
#define BN 128
#define BK 64

template <bool A_BF16>
__global__ __launch_bounds__(256) void gemm_bias_kernel(
    const void* __restrict__ Av, const short* __restrict__ Bt,
    const float* __restrict__ bias, float* __restrict__ C,
    int M, int N, int K) {
  __shared__ __align__(16) short As[BM * BK];
  __shared__ __align__(16) short Bs[BN * BK];
  const int tid = threadIdx.x;
  const int bm = blockIdx.y * BM;
  const int bn = blockIdx.x * BN;
  const int wid = tid >> 6, lane = tid & 63;
  const int wr = wid >> 1, wc = wid & 1;
  const int lrow = lane & 15;
  const int lk = (lane >> 4) * 8;

  f32x4 acc[4][4] = {};

  for (int kt = 0; kt < K; kt += BK) {
    if constexpr (A_BF16) {
      const short* A = (const short*)Av;
#pragma unroll
      for (int r = 0; r < 4; ++r) {
        const int c = r * 256 + tid;
        const int row = c >> 3, ch = c & 7;
        gload_lds16(A + (size_t)(bm + row) * K + kt + ch * 8,
                    (char*)As + c * 16);
      }
    } else {
      const float* A = (const float*)Av;
#pragma unroll
      for (int r = 0; r < 4; ++r) {
        const int c = r * 256 + tid;
        const int row = c >> 3, ch = c & 7;
        const float* src = A + (size_t)(bm + row) * K + kt + ch * 8;
        float4 f0 = *(const float4*)src;
        float4 f1 = *(const float4*)(src + 4);
        short8 v;
        v[0] = f2bf(f0.x); v[1] = f2bf(f0.y); v[2] = f2bf(f0.z); v[3] = f2bf(f0.w);
        v[4] = f2bf(f1.x); v[5] = f2bf(f1.y); v[6] = f2bf(f1.z); v[7] = f2bf(f1.w);
        *(short8*)((char*)As + c * 16) = v;
      }
    }
#pragma unroll
    for (int r = 0; r < 4; ++r) {
      const int c = r * 256 + tid;
      const int row = c >> 3, ch = c & 7;
      gload_lds16(Bt + (size_t)(bn + row) * K + kt + ch * 8,
                  (char*)Bs + c * 16);
    }
    __syncthreads();
#pragma unroll
    for (int kk = 0; kk < 2; ++kk) {
      short8 af[4], bf[4];
#pragma unroll
      for (int i = 0; i < 4; ++i)
        af[i] = *(const short8*)&As[(wr * 64 + i * 16 + lrow) * BK + kk * 32 + lk];
#pragma unroll
      for (int j = 0; j < 4; ++j)
        bf[j] = *(const short8*)&Bs[(wc * 64 + j * 16 + lrow) * BK + kk * 32 + lk];
#pragma unroll
      for (int i = 0; i < 4; ++i)
#pragma unroll
        for (int j = 0; j < 4; ++j)
          acc[i][j] = __builtin_amdgcn_mfma_f32_16x16x32_bf16(
              af[i], bf[j], acc[i][j], 0, 0, 0);
    }
    __syncthreads();
  }

  const int crow0 = bm + wr * 64 + (lane >> 4) * 4;
  const int ccol0 = bn + wc * 64 + (lane & 15);
#pragma unroll
  for (int j = 0; j < 4; ++j) {
    const float bv = bias[ccol0 + j * 16];
#pragma unroll
    for (int i = 0; i < 4; ++i) {
#pragma unroll
      for (int r = 0; r < 4; ++r) {
        C[(size_t)(crow0 + i * 16 + r) * N + ccol0 + j * 16] = acc[i][j][r] + bv;
      }
    }
  }
}

// ---------------------------------------------------------------------------
// Last-resort fallback: naive fused dequant GEMM.
// ---------------------------------------------------------------------------
__global__ __launch_bounds__(256) void naive_kernel(
    const float* __restrict__ x, const float* __restrict__ scales,
    const float* __restrict__ bias, const int* __restrict__ qw,
    const int* __restrict__ qz, float* __restrict__ out,
    int M, int K, int N) {
  long idx = (long)blockIdx.x * blockDim.x + threadIdx.x;
  if (idx >= (long)M * N) return;
  const int n = (int)(idx % N);
  const int m = (int)(idx / N);
  float acc = 0.f;
  for (int g = 0; g < K / 128; ++g) {
    const float sc = scales[(size_t)g * N + n];
    const float zp =
        (float)(((qz[(size_t)g * (N >> 3) + (n >> 3)] >> ((n & 7) * 4)) & 15) + 1);
    const float zs = zp * sc;
    for (int kw = 0; kw < 16; ++kw) {
      const int w = qw[(size_t)(g * 16 + kw) * N + n];
      const float* xp = &x[(size_t)m * K + g * 128 + kw * 8];
#pragma unroll
      for (int e = 0; e < 8; ++e)
        acc += xp[e] * ((float)((w >> (4 * e)) & 15) * sc - zs);
    }
  }
  out[idx] = acc + bias[n];
}

// ---------------------------------------------------------------------------
extern "C" void kernel_launch(void* const* d_in, const int* in_sizes, int n_in,
                              void* d_out, int out_size, void* d_ws,
                              size_t ws_size, hipStream_t stream) {
  const float* x = (const float*)d_in[0];
  const float* scales = (const float*)d_in[1];
  const float* bias = (const float*)d_in[2];
  const int* qweight = (const int*)d_in[3];
  const int* qzeros = (const int*)d_in[4];
  float* out = (float*)d_out;

  const int out_f = in_sizes[2];            // 12288
  const int kwords = in_sizes[3] / out_f;   // 512
  const int in_f = kwords * 8;              // 4096
  const int tokens = in_sizes[0] / in_f;    // 8192
  const int M = tokens, K = in_f, N = out_f;

  const size_t wt_bytes = (size_t)K * N * sizeof(short);
  const size_t xb_bytes = (size_t)M * K * sizeof(short);

  const bool div128 = (M % BM == 0) && (N % BN == 0) && (K % BK == 0) &&
                      (K % 128 == 0) && (N % 64 == 0);
  const bool div256 = (M % GBM == 0) && (N % GBN == 0) && (K % 256 == 0);

  if (div256 && ws_size >= wt_bytes + xb_bytes) {
    // R15 pre-tiled path
    short* Btile = (short*)d_ws;                        // B' fragment tiles
    short* Atile = (short*)((char*)d_ws + wt_bytes);    // A' fragment tiles
    const int ktn = K >> 6;
    dequant_tile_kernel<<<(N / 256) * ktn, 256, 0, stream>>>(
        qweight, qzeros, scales, Btile, N, K);
    cvt_tile_kernel<<<(M / 256) * ktn, 256, 0, stream>>>(x, Atile, K);
    gemm256_kernel<<<(M / GBM) * (N / GBN), 512, 0, stream>>>(
        Atile, Btile, bias, out, M, N, K);
  } else if (div128 && ws_size >= wt_bytes + xb_bytes) {
    short* Wt = (short*)d_ws;
    short* xb = (short*)((char*)d_ws + wt_bytes);
    dequant_kernel<<<dim3(N / 64, K / 64), 256, 0, stream>>>(
        qweight, qzeros, scales, Wt, K, N);
    const long n8 = (long)M * K / 8;
    cvt_kernel<<<(int)((n8 + 255) / 256), 256, 0, stream>>>(x, xb, n8);
    gemm_bias_kernel<true><<<dim3(N / BN, M / BM), 256, 0, stream>>>(
        xb, Wt, bias, out, M, N, K);
  } else if (div128 && ws_size >= wt_bytes) {
    short* Wt = (short*)d_ws;
    dequant_kernel<<<dim3(N / 64, K / 64), 256, 0, stream>>>(
        qweight, qzeros, scales, Wt, K, N);
    gemm_bias_kernel<false><<<dim3(N / BN, M / BM), 256, 0, stream>>>(
        x, Wt, bias, out, M, N, K);
  } else {
    const long total = (long)M * N;
    naive_kernel<<<(int)((total + 255) / 256), 256, 0, stream>>>(
        x, scales, bias, qweight, qzeros, out, M, K, N);
  }
}

// Round 16
// 771.249 us; speedup vs baseline: 1.1029x; 1.0381x over previous
//
#include <hip/hip_runtime.h>
#include <hip/hip_bf16.h>

// ---------------------------------------------------------------------------
// WeightOnlyLinear: y = x @ dequant4(qweight, scales, qzeros) + bias
//   x (8192,4096) fp32 | scales (32,12288) | bias (12288) | qweight (512,12288)
//   qzeros (32,1536) | out (8192,12288) fp32
// R16: TWO CO-RESIDENT BLOCKS PER CU. Tile 256x128, 8 waves (2Mx4N), wave
//   128x32 (acc 64 AGPR), ring-3 x 24KB LDS slots (72KB/block), launch_bounds
//   (512,4) caps regs at 128 -> 16 waves/CU from 2 independent blocks whose
//   barriers interleave. Pre-tiled fragment-major A'(256,32)/B'(128,32) tiles
//   keep staging (3 gloads/thread) and ds_reads (10 frags) linear/0-conflict.
//   Ledger (ring-3): per phase {vm3; bar; reads; stage(q+2); 16 MFMA};
//   P=K/32=128 phases = 42x3 body + 2 peeled (vm3 / vm0).
// ---------------------------------------------------------------------------

typedef __attribute__((ext_vector_type(8))) short short8;
typedef __attribute__((ext_vector_type(4))) float f32x4;

__device__ __forceinline__ short f2bf(float f) {
  unsigned u = __float_as_uint(f);
  u += 0x7fffu + ((u >> 16) & 1u);
  return (short)(u >> 16);
}

__device__ __forceinline__ void gload_lds16(const void* g, void* l) {
  __builtin_amdgcn_global_load_lds(
      (const __attribute__((address_space(1))) void*)g,
      (__attribute__((address_space(3))) void*)l,
      16, 0, 0);
}

__device__ __forceinline__ void bar() {
  asm volatile("" ::: "memory");
  __builtin_amdgcn_s_barrier();
  asm volatile("" ::: "memory");
}
__device__ __forceinline__ void wait_vm3() {
  asm volatile("s_waitcnt vmcnt(3)" ::: "memory");
}
__device__ __forceinline__ void wait_vm0() {
  asm volatile("s_waitcnt vmcnt(0)" ::: "memory");
}

// ---------------------------------------------------------------------------
// Pass 1 (R16): dequant qweight -> B' fragment-major (nb128, kt32) 8KB tiles.
// Chunk c (16B): cb=c>>6, l=c&63; col = nb*128 + cb*16 + (l&15);
// k = kt*32 + (l>>4)*8. One qweight word == one chunk.
// grid = (N/128)*(K/32), 256 thr, 2 chunks/thr.
// ---------------------------------------------------------------------------
__global__ __launch_bounds__(256) void dequant_tile_kernel(
    const int* __restrict__ qweight, const int* __restrict__ qzeros,
    const float* __restrict__ scales, short* __restrict__ Bt,
    int N, int K) {
  const int ktn = K >> 5;
  const int bx = blockIdx.x;
  const int nb = bx / ktn, kt = bx - nb * ktn;
  const int t = threadIdx.x;
  const int g = kt >> 2;  // GROUPSIZE=128 = 4 k32-tiles
  char* dst = (char*)Bt + (size_t)bx * 8192;
#pragma unroll
  for (int p = 0; p < 2; ++p) {
    const int c = p * 256 + t;
    const int l = c & 63;
    const int n = nb * 128 + (c >> 6) * 16 + (l & 15);
    const int kw = kt * 4 + (l >> 4);
    const float sc = scales[(size_t)g * N + n];
    const int zw = qzeros[(size_t)g * (N >> 3) + (n >> 3)];
    const float zs = -(float)(((zw >> ((n & 7) * 4)) & 15) + 1) * sc;
    const int w = qweight[(size_t)kw * N + n];
    short8 v;
#pragma unroll
    for (int e = 0; e < 8; ++e)
      v[e] = f2bf(fmaf((float)((w >> (4 * e)) & 15), sc, zs));
    *(short8*)(dst + c * 16) = v;
  }
}

// ---------------------------------------------------------------------------
// Pass 2 (R16): x fp32 -> A' fragment-major (mb256, kt32) 16KB tiles.
// Chunk c: rb=c>>6, l=c&63; row = mb*256 + rb*16 + (l&15); k = kt*32+(l>>4)*8.
// grid = (M/256)*(K/32), 256 thr, 4 chunks/thr.
// ---------------------------------------------------------------------------
__global__ __launch_bounds__(256) void cvt_tile_kernel(
    const float* __restrict__ x, short* __restrict__ xb, int K) {
  const int ktn = K >> 5;
  const int bx = blockIdx.x;
  const int mb = bx / ktn, kt = bx - mb * ktn;
  char* dst = (char*)xb + (size_t)bx * 16384;
#pragma unroll
  for (int p = 0; p < 4; ++p) {
    const int c = p * 256 + threadIdx.x;
    const int l = c & 63;
    const int row = mb * 256 + (c >> 6) * 16 + (l & 15);
    const int k = kt * 32 + (l >> 4) * 8;
    const float* s = x + (size_t)row * K + k;
    float4 f0 = *(const float4*)s;
    float4 f1 = *(const float4*)(s + 4);
    short8 v;
    v[0] = f2bf(f0.x); v[1] = f2bf(f0.y); v[2] = f2bf(f0.z); v[3] = f2bf(f0.w);
    v[4] = f2bf(f1.x); v[5] = f2bf(f1.y); v[6] = f2bf(f1.z); v[7] = f2bf(f1.w);
    *(short8*)(dst + c * 16) = v;
  }
}

// ---------------------------------------------------------------------------
// Pass 3 (R16): 256x128 GEMM, 512 threads = 8 waves (2M x 4N), wave 128x32.
// MFMA 16x16x32; acc f32x4[8][2]. LDS: ring-3 x 24576 (A 16KB @0, B 8KB
// @16384). Phase q (slot q%3): {vm3; bar; 10 frag reads; stage tile q+2 ->
// slot (q+2)%3 [3 gloads]; setprio 16 MFMA}. Tail peel: vm3 / vm0.
// ---------------------------------------------------------------------------
#define GBM 256
#define GBN 128

__global__ __launch_bounds__(512, 4) void gemm256_kernel(
    const short* __restrict__ At, const short* __restrict__ Bt,
    const float* __restrict__ bias, float* __restrict__ C,
    int M, int N, int K) {
  __shared__ __align__(16) char lds[3 * 24576];
  const int tid = threadIdx.x;
  const int nbx = N / GBN;
  const int nwg = gridDim.x;
  int bid = blockIdx.x;
  if ((nwg & 7) == 0) bid = (bid & 7) * (nwg >> 3) + (bid >> 3);  // T1
  const int mb = bid / nbx;
  const int nb = bid % nbx;
  const int bm = mb * GBM, bn = nb * GBN;

  const int wid = tid >> 6, lane = tid & 63;
  const int wr = wid >> 2, wc = wid & 3;  // 2x4 wave grid

  const int P = K >> 5;  // K-32 tiles; launcher guarantees (P-2)%3==0

  char* lb = &lds[0];

  // frag read bases (all further offsets are compile-time immediates)
  const char* aBase = lb + wr * 8192 + lane * 16;           // + SL*24576 + i*1024
  const char* bBase = lb + 16384 + wc * 2048 + lane * 16;   // + SL*24576 + j*1024

  // staging: A chunks {tid, tid+512}, B chunk {tid}; linear dst
  const char* pA = (const char*)At + (size_t)mb * P * 16384 + (size_t)tid * 16;
  const char* pB = (const char*)Bt + (size_t)nb * P * 8192 + (size_t)tid * 16;
  char* dA = lb + tid * 16;
  char* dB = lb + 16384 + tid * 16;

#define STAGE(TSL, AOFF, BOFF)                         \
  do {                                                 \
    gload_lds16(pA + (AOFF), dA + (TSL)*24576);        \
    gload_lds16(pA + (AOFF) + 8192, dA + (TSL)*24576 + 8192); \
    gload_lds16(pB + (BOFF), dB + (TSL)*24576);        \
  } while (0)

  short8 aR[8], bR[2];

#define RD(SL)                                                        \
  do {                                                                \
    _Pragma("unroll") for (int i = 0; i < 8; ++i) aR[i] =             \
        *(const short8*)(aBase + (SL)*24576 + i * 1024);              \
    _Pragma("unroll") for (int j = 0; j < 2; ++j) bR[j] =             \
        *(const short8*)(bBase + (SL)*24576 + j * 1024);              \
  } while (0)

  f32x4 acc[8][2] = {};

#define MFMA16()                                                      \
  do {                                                                \
    __builtin_amdgcn_s_setprio(1);                                    \
    _Pragma("unroll") for (int i = 0; i < 8; ++i)                     \
        _Pragma("unroll") for (int j = 0; j < 2; ++j) acc[i][j] =     \
            __builtin_amdgcn_mfma_f32_16x16x32_bf16(aR[i], bR[j],     \
                                                    acc[i][j], 0, 0, 0); \
    __builtin_amdgcn_s_setprio(0);                                    \
  } while (0)

  // prologue: tile0 -> slot0, tile1 -> slot1 (6 gloads)
  STAGE(0, 0, 0);
  STAGE(1, 16384, 8192);

  // body: 42 iterations x 3 phases (q = 3it+{0,1,2}, slots {0,1,2});
  // phase q stages tile q+2 -> slot (q+2)%3.
  const int nIt = (P - 2) / 3;
  for (int it = 0; it < nIt; ++it) {
    wait_vm3(); bar();
    RD(0); STAGE(2, 2 * 16384, 2 * 8192); MFMA16();
    wait_vm3(); bar();
    RD(1); STAGE(0, 3 * 16384, 3 * 8192); MFMA16();
    wait_vm3(); bar();
    RD(2); STAGE(1, 4 * 16384, 4 * 8192); MFMA16();
    pA += 3 * 16384;
    pB += 3 * 8192;
  }
  // peel: q = P-2 (slot 0), q = P-1 (slot 1)
  wait_vm3(); bar();
  RD(0); MFMA16();
  wait_vm0(); bar();
  RD(1); MFMA16();

#undef MFMA16
#undef RD
#undef STAGE

  // epilogue: C = acc + bias. 16x16 C/D: col=lane&15, row=(lane>>4)*4+r
  const int crow0 = bm + wr * 128 + (lane >> 4) * 4;
  const int ccol0 = bn + wc * 32 + (lane & 15);
#pragma unroll
  for (int fj = 0; fj < 2; ++fj) {
    const float bv = bias[ccol0 + fj * 16];
#pragma unroll
    for (int fi = 0; fi < 8; ++fi) {
#pragma unroll
      for (int r = 0; r < 4; ++r) {
        C[(size_t)(crow0 + fi * 16 + r) * N + ccol0 + fj * 16] =
            acc[fi][fj][r] + bv;
      }
    }
  }
}

// ---------------------------------------------------------------------------
// Fallback prepasses (linear layouts) for non-divisible shapes.
// ---------------------------------------------------------------------------
__global__ __launch_bounds__(256) void dequant_kernel(
    const int* __restrict__ qweight, const int* __restrict__ qzeros,
    const float* __restrict__ scales, short* __restrict__ Wt,
    int in_f, int out_f) {
  __shared__ __align__(16) short T[64][72];
  const int n0 = blockIdx.x * 64;
  const int k0 = blockIdx.y * 64;
  const int t = threadIdx.x;
  const int nl = t & 63;
  const int kw = t >> 6;
  const int n = n0 + nl;
  const int g = k0 >> 7;
  const float sc = scales[(size_t)g * out_f + n];
  const int zpw = qzeros[(size_t)g * (out_f >> 3) + (n >> 3)];
  const float zp = (float)(((zpw >> ((n & 7) * 4)) & 15) + 1);
  const float zs = zp * sc;
#pragma unroll
  for (int rr = 0; rr < 2; ++rr) {
    const int kwi = kw + rr * 4;
    const int w = qweight[(size_t)((k0 >> 3) + kwi) * out_f + n];
    short8 v;
#pragma unroll
    for (int e = 0; e < 8; ++e) {
      float f = (float)((w >> (4 * e)) & 15) * sc - zs;
      v[e] = f2bf(f);
    }
    *(short8*)&T[nl][kwi * 8] = v;
  }
  __syncthreads();
#pragma unroll
  for (int rr = 0; rr < 2; ++rr) {
    const int c = rr * 256 + t;
    const int row = c >> 3, ch = c & 7;
    *(short8*)&Wt[(size_t)(n0 + row) * in_f + k0 + ch * 8] =
        *(const short8*)&T[row][ch * 8];
  }
}

__global__ __launch_bounds__(256) void cvt_kernel(
    const float* __restrict__ x, short* __restrict__ xb, long n8) {
  long i = (long)blockIdx.x * blockDim.x + threadIdx.x;
  if (i >= n8) return;
  const float* src = x + i * 8;
  float4 a = *(const float4*)src;
  float4 b = *(const float4*)(src + 4);
  short8 v;
  v[0] = f2bf(a.x); v[1] = f2bf(a.y); v[2] = f2bf(a.z); v[3] = f2bf(a.w);
  v[4] = f2bf(b.x); v[5] = f2bf(b.y); v[6] = f2bf(b.z); v[7] = f2bf(b.w);
  *(short8*)(xb + i * 8) = v;
}

// ---------------------------------------------------------------------------
// 128x128x64 GEMM (fallback for non-divisible shapes).
// ---------------------------------------------------------------------------
#define BM 128
#define BN 128
#define BK 64

template <bool A_BF16>
__global__ __launch_bounds__(256) void gemm_bias_kernel(
    const void* __restrict__ Av, const short* __restrict__ Bt,
    const float* __restrict__ bias, float* __restrict__ C,
    int M, int N, int K) {
  __shared__ __align__(16) short As[BM * BK];
  __shared__ __align__(16) short Bs[BN * BK];
  const int tid = threadIdx.x;
  const int bm = blockIdx.y * BM;
  const int bn = blockIdx.x * BN;
  const int wid = tid >> 6, lane = tid & 63;
  const int wr = wid >> 1, wc = wid & 1;
  const int lrow = lane & 15;
  const int lk = (lane >> 4) * 8;

  f32x4 acc[4][4] = {};

  for (int kt = 0; kt < K; kt += BK) {
    if constexpr (A_BF16) {
      const short* A = (const short*)Av;
#pragma unroll
      for (int r = 0; r < 4; ++r) {
        const int c = r * 256 + tid;
        const int row = c >> 3, ch = c & 7;
        gload_lds16(A + (size_t)(bm + row) * K + kt + ch * 8,
                    (char*)As + c * 16);
      }
    } else {
      const float* A = (const float*)Av;
#pragma unroll
      for (int r = 0; r < 4; ++r) {
        const int c = r * 256 + tid;
        const int row = c >> 3, ch = c & 7;
        const float* src = A + (size_t)(bm + row) * K + kt + ch * 8;
        float4 f0 = *(const float4*)src;
        float4 f1 = *(const float4*)(src + 4);
        short8 v;
        v[0] = f2bf(f0.x); v[1] = f2bf(f0.y); v[2] = f2bf(f0.z); v[3] = f2bf(f0.w);
        v[4] = f2bf(f1.x); v[5] = f2bf(f1.y); v[6] = f2bf(f1.z); v[7] = f2bf(f1.w);
        *(short8*)((char*)As + c * 16) = v;
      }
    }
#pragma unroll
    for (int r = 0; r < 4; ++r) {
      const int c = r * 256 + tid;
      const int row = c >> 3, ch = c & 7;
      gload_lds16(Bt + (size_t)(bn + row) * K + kt + ch * 8,
                  (char*)Bs + c * 16);
    }
    __syncthreads();
#pragma unroll
    for (int kk = 0; kk < 2; ++kk) {
      short8 af[4], bf[4];
#pragma unroll
      for (int i = 0; i < 4; ++i)
        af[i] = *(const short8*)&As[(wr * 64 + i * 16 + lrow) * BK + kk * 32 + lk];
#pragma unroll
      for (int j = 0; j < 4; ++j)
        bf[j] = *(const short8*)&Bs[(wc * 64 + j * 16 + lrow) * BK + kk * 32 + lk];
#pragma unroll
      for (int i = 0; i < 4; ++i)
#pragma unroll
        for (int j = 0; j < 4; ++j)
          acc[i][j] = __builtin_amdgcn_mfma_f32_16x16x32_bf16(
              af[i], bf[j], acc[i][j], 0, 0, 0);
    }
    __syncthreads();
  }

  const int crow0 = bm + wr * 64 + (lane >> 4) * 4;
  const int ccol0 = bn + wc * 64 + (lane & 15);
#pragma unroll
  for (int j = 0; j < 4; ++j) {
    const float bv = bias[ccol0 + j * 16];
#pragma unroll
    for (int i = 0; i < 4; ++i) {
#pragma unroll
      for (int r = 0; r < 4; ++r) {
        C[(size_t)(crow0 + i * 16 + r) * N + ccol0 + j * 16] = acc[i][j][r] + bv;
      }
    }
  }
}

// ---------------------------------------------------------------------------
// Last-resort fallback: naive fused dequant GEMM.
// ---------------------------------------------------------------------------
__global__ __launch_bounds__(256) void naive_kernel(
    const float* __restrict__ x, const float* __restrict__ scales,
    const float* __restrict__ bias, const int* __restrict__ qw,
    const int* __restrict__ qz, float* __restrict__ out,
    int M, int K, int N) {
  long idx = (long)blockIdx.x * blockDim.x + threadIdx.x;
  if (idx >= (long)M * N) return;
  const int n = (int)(idx % N);
  const int m = (int)(idx / N);
  float acc = 0.f;
  for (int g = 0; g < K / 128; ++g) {
    const float sc = scales[(size_t)g * N + n];
    const float zp =
        (float)(((qz[(size_t)g * (N >> 3) + (n >> 3)] >> ((n & 7) * 4)) & 15) + 1);
    const float zs = zp * sc;
    for (int kw = 0; kw < 16; ++kw) {
      const int w = qw[(size_t)(g * 16 + kw) * N + n];
      const float* xp = &x[(size_t)m * K + g * 128 + kw * 8];
#pragma unroll
      for (int e = 0; e < 8; ++e)
        acc += xp[e] * ((float)((w >> (4 * e)) & 15) * sc - zs);
    }
  }
  out[idx] = acc + bias[n];
}

// ---------------------------------------------------------------------------
extern "C" void kernel_launch(void* const* d_in, const int* in_sizes, int n_in,
                              void* d_out, int out_size, void* d_ws,
                              size_t ws_size, hipStream_t stream) {
  const float* x = (const float*)d_in[0];
  const float* scales = (const float*)d_in[1];
  const float* bias = (const float*)d_in[2];
  const int* qweight = (const int*)d_in[3];
  const int* qzeros = (const int*)d_in[4];
  float* out = (float*)d_out;

  const int out_f = in_sizes[2];            // 12288
  const int kwords = in_sizes[3] / out_f;   // 512
  const int in_f = kwords * 8;              // 4096
  const int tokens = in_sizes[0] / in_f;    // 8192
  const int M = tokens, K = in_f, N = out_f;

  const size_t wt_bytes = (size_t)K * N * sizeof(short);
  const size_t xb_bytes = (size_t)M * K * sizeof(short);

  const bool div128 = (M % BM == 0) && (N % BN == 0) && (K % BK == 0) &&
                      (K % 128 == 0) && (N % 64 == 0);
  const bool divR16 = (M % GBM == 0) && (N % GBN == 0) && (K % 256 == 0) &&
                      (((K >> 5) - 2) % 3 == 0);

  if (divR16 && ws_size >= wt_bytes + xb_bytes) {
    // R16 pre-tiled path
    short* Btile = (short*)d_ws;                        // B' fragment tiles
    short* Atile = (short*)((char*)d_ws + wt_bytes);    // A' fragment tiles
    const int ktn = K >> 5;
    dequant_tile_kernel<<<(N / 128) * ktn, 256, 0, stream>>>(
        qweight, qzeros, scales, Btile, N, K);
    cvt_tile_kernel<<<(M / 256) * ktn, 256, 0, stream>>>(x, Atile, K);
    gemm256_kernel<<<(M / GBM) * (N / GBN), 512, 0, stream>>>(
        Atile, Btile, bias, out, M, N, K);
  } else if (div128 && ws_size >= wt_bytes + xb_bytes) {
    short* Wt = (short*)d_ws;
    short* xb = (short*)((char*)d_ws + wt_bytes);
    dequant_kernel<<<dim3(N / 64, K / 64), 256, 0, stream>>>(
        qweight, qzeros, scales, Wt, K, N);
    const long n8 = (long)M * K / 8;
    cvt_kernel<<<(int)((n8 + 255) / 256), 256, 0, stream>>>(x, xb, n8);
    gemm_bias_kernel<true><<<dim3(N / BN, M / BM), 256, 0, stream>>>(
        xb, Wt, bias, out, M, N, K);
  } else if (div128 && ws_size >= wt_bytes) {
    short* Wt = (short*)d_ws;
    dequant_kernel<<<dim3(N / 64, K / 64), 256, 0, stream>>>(
        qweight, qzeros, scales, Wt, K, N);
    gemm_bias_kernel<false><<<dim3(N / BN, M / BM), 256, 0, stream>>>(
        x, Wt, bias, out, M, N, K);
  } else {
    const long total = (long)M * N;
    naive_kernel<<<(int)((total + 255) / 256), 256, 0, stream>>>(
        x, scales, bias, qweight, qzeros, out, M, K, N);
  }
}